// Round 1
// baseline (168.829 us; speedup 1.0000x reference)
//
#include <hip/hip_runtime.h>
#include <math.h>

#define FEAT 256
#define NB   16
#define TLEN 4096
#define NROWS (NB * TLEN)

// ws layout (element offsets, 4B elements; total ~2.1 MB)
#define OFF_WEFF 0                      // float[5][256]
#define OFF_BEFF 1280                   // float
#define OFF_P    2048                   // float[5][NB][TLEN]
#define OFF_W1   (OFF_P + 5 * NROWS)    // float[NB][TLEN]
#define OFF_W2   (OFF_W1 + NROWS)       // float[NB][TLEN]
#define OFF_FPOS (OFF_W2 + NROWS)       // int[NB][TLEN]
#define OFF_NF   (OFF_FPOS + NROWS)     // int[NB]

// Kernel A: collapse conv+linear into w_eff[k][i] and scalar b_eff.
__global__ __launch_bounds__(256) void weff_kernel(
    const float* __restrict__ conv_w, const float* __restrict__ conv_b,
    const float* __restrict__ lin_w, const float* __restrict__ lin_b,
    float* __restrict__ ws) {
  if (blockIdx.x < 5) {
    int idx = blockIdx.x * 256 + threadIdx.x;   // idx = i*5 + k  (coalesced in o-loop)
    int i = idx / 5, k = idx - i * 5;
    float acc = 0.f;
    for (int o = 0; o < FEAT; ++o)
      acc = fmaf(conv_w[o * (FEAT * 5) + idx], lin_w[o], acc);
    ws[OFF_WEFF + k * FEAT + i] = acc;
  } else {
    __shared__ float red[256];
    red[threadIdx.x] = conv_b[threadIdx.x] * lin_w[threadIdx.x];
    __syncthreads();
    for (int s = 128; s > 0; s >>= 1) {
      if (threadIdx.x < s) red[threadIdx.x] += red[threadIdx.x + s];
      __syncthreads();
    }
    if (threadIdx.x == 0) ws[OFF_BEFF] = red[0] + lin_b[0];
  }
}

// Kernel B: P[k][b][t] = dot(x[b,t,:], w_eff[k,:]).  One wave per row.
__global__ __launch_bounds__(256) void pdot_kernel(
    const float* __restrict__ x, float* __restrict__ ws) {
  int gtid = blockIdx.x * 256 + threadIdx.x;
  int row  = gtid >> 6;          // b*TLEN + t
  int lane = gtid & 63;
  float4 xv = *(const float4*)(x + (size_t)row * FEAT + lane * 4);
  float p[5];
#pragma unroll
  for (int k = 0; k < 5; ++k) {
    float4 w4 = *(const float4*)(ws + OFF_WEFF + k * FEAT + lane * 4);
    p[k] = fmaf(xv.x, w4.x, fmaf(xv.y, w4.y, fmaf(xv.z, w4.z, xv.w * w4.w)));
#pragma unroll
    for (int off = 32; off; off >>= 1) p[k] += __shfl_xor(p[k], off);
  }
  if (lane == 0) {
#pragma unroll
    for (int k = 0; k < 5; ++k) ws[OFF_P + (size_t)k * NROWS + row] = p[k];
  }
}

// Kernel C: per-batch.  alphas = sigmoid(sum_k P[k][t+k-2] + b_eff);
// f64 block prefix sum S_t; F_t = floor(S_t); emit per-step weights +
// fire positions.  Exact-math-equivalent to the reference scan; borderline
// fire flips vs the reference's f32 recurrence self-heal with O(eps) error.
__global__ __launch_bounds__(256) void scan_kernel(
    float* __restrict__ ws, float* __restrict__ out) {
  const int b = blockIdx.x;
  __shared__ float  s_alpha[TLEN];   // 16 KB
  __shared__ double s_S[TLEN];       // 32 KB
  __shared__ double s_part[256];     //  2 KB
  const float b_eff = ws[OFF_BEFF];

  for (int j = 0; j < TLEN / 256; ++j) {
    int t = j * 256 + threadIdx.x;
    float z = b_eff;
#pragma unroll
    for (int k = 0; k < 5; ++k) {
      int tt = t + k - 2;
      if (tt >= 0 && tt < TLEN) z += ws[OFF_P + (size_t)k * NROWS + b * TLEN + tt];
    }
    s_alpha[t] = 1.f / (1.f + expf(-z));
  }
  __syncthreads();

  const int base = threadIdx.x * 16;
  double run = 0.0;
#pragma unroll
  for (int r = 0; r < 16; ++r) { run += (double)s_alpha[base + r]; s_S[base + r] = run; }
  s_part[threadIdx.x] = run;
  __syncthreads();
  for (int s = 1; s < 256; s <<= 1) {          // Hillis-Steele over 256 partials
    double add = (threadIdx.x >= s) ? s_part[threadIdx.x - s] : 0.0;
    __syncthreads();
    if (threadIdx.x >= s) s_part[threadIdx.x] += add;
    __syncthreads();
  }
  double offset = threadIdx.x ? s_part[threadIdx.x - 1] : 0.0;

  double Sprev = offset;
  double Fprev = floor(Sprev);
  float* w1 = ws + OFF_W1 + b * TLEN;
  float* w2 = ws + OFF_W2 + b * TLEN;
  int* fpos = (int*)ws + OFF_FPOS + b * TLEN;
#pragma unroll
  for (int r = 0; r < 16; ++r) {
    int t = base + r;
    double St = offset + s_S[t];
    double Ft = floor(St);
    w1[t] = (float)(fmin(St, Fprev + 1.0) - Sprev);   // alpha_t, or a1 at fire
    if (Ft > Fprev) {
      w2[t] = (float)(St - Ft);                       // a2 -> next segment
      fpos[(int)Ft - 1] = t;                          // emission index F_t-1
    }
    Sprev = St; Fprev = Ft;
  }
  if (threadIdx.x == 255) {
    int n = (int)Fprev;                               // floor(S_{T-1}) = total fires
    ((int*)ws)[OFF_NF + b] = n;
    out[(size_t)NROWS * FEAT + b] = (float)(n > 0 ? n : 1);   // len output
  }
}

// Kernel D: one wave per output row j: gather weighted segment
// [t_lo..t_hi] of x; rows >= keep are zeros.
__global__ __launch_bounds__(256) void emit_kernel(
    const float* __restrict__ x, const float* __restrict__ ws,
    float* __restrict__ out) {
  int gtid = blockIdx.x * 256 + threadIdx.x;
  int row  = gtid >> 6;          // b*TLEN + j
  int lane = gtid & 63;
  int b = row >> 12;             // / TLEN
  int j = row & (TLEN - 1);
  int n = ((const int*)ws)[OFF_NF + b];
  int keep = n > 0 ? n : 1;
  float4 acc = make_float4(0.f, 0.f, 0.f, 0.f);
  if (j < keep) {
    const int* fpos = (const int*)ws + OFF_FPOS + b * TLEN;
    int t_lo = j ? fpos[j - 1] : 0;
    int t_hi = (j < n) ? fpos[j] : TLEN - 1;          // n==0: whole-seq hacc_f
    const float* w1 = ws + OFF_W1 + b * TLEN;
    const float* w2 = ws + OFF_W2 + b * TLEN;
    for (int t = t_lo; t <= t_hi; ++t) {
      float w = (j && t == t_lo) ? w2[t] : w1[t];
      float4 xv = *(const float4*)(x + ((size_t)b * TLEN + t) * FEAT + lane * 4);
      acc.x = fmaf(w, xv.x, acc.x);
      acc.y = fmaf(w, xv.y, acc.y);
      acc.z = fmaf(w, xv.z, acc.z);
      acc.w = fmaf(w, xv.w, acc.w);
    }
  }
  *(float4*)(out + (size_t)row * FEAT + lane * 4) = acc;
}

extern "C" void kernel_launch(void* const* d_in, const int* in_sizes, int n_in,
                              void* d_out, int out_size, void* d_ws, size_t ws_size,
                              hipStream_t stream) {
  const float* x      = (const float*)d_in[0];
  const float* conv_w = (const float*)d_in[1];
  const float* conv_b = (const float*)d_in[2];
  const float* lin_w  = (const float*)d_in[3];
  const float* lin_b  = (const float*)d_in[4];
  float* out = (float*)d_out;
  float* ws  = (float*)d_ws;

  hipLaunchKernelGGL(weff_kernel, dim3(6), dim3(256), 0, stream,
                     conv_w, conv_b, lin_w, lin_b, ws);
  hipLaunchKernelGGL(pdot_kernel, dim3(NROWS / 4), dim3(256), 0, stream, x, ws);
  hipLaunchKernelGGL(scan_kernel, dim3(NB), dim3(256), 0, stream, ws, out);
  hipLaunchKernelGGL(emit_kernel, dim3(NROWS / 4), dim3(256), 0, stream, x, ws, out);
}

// Round 2
// 165.378 us; speedup vs baseline: 1.0209x; 1.0209x over previous
//
#include <hip/hip_runtime.h>
#include <math.h>

#define FEAT 256
#define NB   16
#define TLEN 4096
#define NROWS (NB * TLEN)

// ws layout (element offsets, 4B elements; total ~2.2 MB)
#define OFF_WEFF 0                      // float[5][256]
#define OFF_BEFF 1280                   // float
#define OFF_P    2048                   // float[5][NB][TLEN]
#define OFF_W1   (OFF_P + 5 * NROWS)    // float[NB][TLEN]
#define OFF_W2   (OFF_W1 + NROWS)      // float[NB][TLEN]
#define OFF_FPOS (OFF_W2 + NROWS)      // int[NB][TLEN]
#define OFF_NF   (OFF_FPOS + NROWS)    // int[NB]
#define OFF_PART (OFF_NF + 16)         // float[8][1280] weff partials

// Kernel A1: partial sums over o-chunks for w_eff.  40 blocks (5 idx-groups
// x 8 o-chunks), deterministic two-stage reduce (no atomics).
__global__ __launch_bounds__(256) void weff1_kernel(
    const float* __restrict__ conv_w, const float* __restrict__ lin_w,
    float* __restrict__ ws) {
  int ob = blockIdx.x % 5, oc = blockIdx.x / 5;
  int idx = ob * 256 + threadIdx.x;      // idx = i*5 + k (coalesced over o-rows)
  float acc = 0.f;
  int o0 = oc * 32;
#pragma unroll 8
  for (int o = o0; o < o0 + 32; ++o)
    acc = fmaf(conv_w[o * (FEAT * 5) + idx], lin_w[o], acc);
  ws[OFF_PART + oc * 1280 + idx] = acc;
}

// Kernel A2: reduce 8 partials -> w_eff[k][i]; block 5 computes b_eff.
__global__ __launch_bounds__(256) void weff2_kernel(
    const float* __restrict__ conv_b, const float* __restrict__ lin_w,
    const float* __restrict__ lin_b, float* __restrict__ ws) {
  if (blockIdx.x < 5) {
    int idx = blockIdx.x * 256 + threadIdx.x;
    float acc = 0.f;
#pragma unroll
    for (int c = 0; c < 8; ++c) acc += ws[OFF_PART + c * 1280 + idx];
    int i = idx / 5, k = idx - i * 5;
    ws[OFF_WEFF + k * FEAT + i] = acc;
  } else {
    __shared__ float red[256];
    red[threadIdx.x] = conv_b[threadIdx.x] * lin_w[threadIdx.x];
    __syncthreads();
    for (int s = 128; s > 0; s >>= 1) {
      if (threadIdx.x < s) red[threadIdx.x] += red[threadIdx.x + s];
      __syncthreads();
    }
    if (threadIdx.x == 0) ws[OFF_BEFF] = red[0] + lin_b[0];
  }
}

// Kernel B: P[k][row] = dot(x[row,:], w_eff[k,:]).
// 8-lane groups own one row each (wave = 8 rows); features split as
// f = pass*32 + lane8*4 + 0..3 over 8 passes.  Reduction is only 3 shfl
// levels (offsets 1,2,4) per k -> 15 DS ops per 8 rows (was 30 per row).
__global__ __launch_bounds__(256) void pdot_kernel(
    const float* __restrict__ x, float* __restrict__ ws) {
  int tid  = threadIdx.x;
  int wave = tid >> 6, l = tid & 63;
  int row  = blockIdx.x * 32 + wave * 8 + (l >> 3);
  int l8   = l & 7;
  const float* xr = x + (size_t)row * FEAT + l8 * 4;
  float p[5] = {0.f, 0.f, 0.f, 0.f, 0.f};
#pragma unroll
  for (int pass = 0; pass < 8; ++pass) {
    float4 xv = *(const float4*)(xr + pass * 32);
#pragma unroll
    for (int k = 0; k < 5; ++k) {
      float4 w4 = *(const float4*)(ws + OFF_WEFF + k * FEAT + pass * 32 + l8 * 4);
      p[k] = fmaf(xv.x, w4.x, fmaf(xv.y, w4.y,
              fmaf(xv.z, w4.z, fmaf(xv.w, w4.w, p[k]))));
    }
  }
#pragma unroll
  for (int k = 0; k < 5; ++k) {
    p[k] += __shfl_xor(p[k], 1);
    p[k] += __shfl_xor(p[k], 2);
    p[k] += __shfl_xor(p[k], 4);
  }
  if (l8 == 0) {
#pragma unroll
    for (int k = 0; k < 5; ++k) ws[OFF_P + (size_t)k * NROWS + row] = p[k];
  }
}

// Kernel C: per-batch.  alphas = sigmoid(sum_k P[k][t+k-2] + b_eff);
// f64 prefix sum S_t; F_t = floor(S_t); fire iff F_t > F_{t-1}.
// s_alpha stored with PAD(t)=t+(t>>4) (stride-17 per 16) -> conflict-free
// serial-16 reads.  The 32KB s_S array is gone: the final loop recomputes
// the running sum in the same order (bit-identical).
#define PAD(t) ((t) + ((t) >> 4))
__global__ __launch_bounds__(256) void scan_kernel(
    float* __restrict__ ws, float* __restrict__ out) {
  const int b = blockIdx.x;
  __shared__ float  s_alpha[TLEN + (TLEN >> 4)];  // 17 KB
  __shared__ double s_part[256];                  //  2 KB
  const float b_eff = ws[OFF_BEFF];
  const float* Pb = ws + OFF_P + (size_t)b * TLEN;

  for (int j = 0; j < TLEN / 256; ++j) {
    int t = j * 256 + threadIdx.x;
    float z = b_eff;
#pragma unroll
    for (int k = 0; k < 5; ++k) {
      int tt = t + k - 2;
      if (tt >= 0 && tt < TLEN) z += Pb[(size_t)k * NROWS + tt];
    }
    s_alpha[PAD(t)] = 1.f / (1.f + expf(-z));
  }
  __syncthreads();

  const int base = threadIdx.x * 16;
  double run = 0.0;
#pragma unroll
  for (int r = 0; r < 16; ++r) run += (double)s_alpha[PAD(base + r)];
  s_part[threadIdx.x] = run;
  __syncthreads();
  for (int s = 1; s < 256; s <<= 1) {            // Hillis-Steele, 256 f64 partials
    double add = (threadIdx.x >= s) ? s_part[threadIdx.x - s] : 0.0;
    __syncthreads();
    if (threadIdx.x >= s) s_part[threadIdx.x] += add;
    __syncthreads();
  }
  double offset = threadIdx.x ? s_part[threadIdx.x - 1] : 0.0;

  double Sprev = offset;
  double Fprev = floor(Sprev);
  float* w1 = ws + OFF_W1 + b * TLEN;
  float* w2 = ws + OFF_W2 + b * TLEN;
  int* fpos = (int*)ws + OFF_FPOS + b * TLEN;
  double runl = 0.0;
#pragma unroll
  for (int r = 0; r < 16; ++r) {
    int t = base + r;
    runl += (double)s_alpha[PAD(t)];
    double St = offset + runl;                   // == old s_S[t] + offset exactly
    double Ft = floor(St);
    w1[t] = (float)(fmin(St, Fprev + 1.0) - Sprev);   // alpha_t, or a1 at fire
    if (Ft > Fprev) {
      w2[t] = (float)(St - Ft);                       // a2 -> next segment
      fpos[(int)Ft - 1] = t;                          // emission index F_t-1
    }
    Sprev = St; Fprev = Ft;
  }
  if (threadIdx.x == 255) {
    int n = (int)Fprev;                               // floor(S_{T-1}) = total fires
    ((int*)ws)[OFF_NF + b] = n;
    out[(size_t)NROWS * FEAT + b] = (float)(n > 0 ? n : 1);   // len output
  }
}

// Kernel D: one wave per output row j: gather weighted segment
// [t_lo..t_hi] of x; rows >= keep are zeros (d_out is poisoned).
__global__ __launch_bounds__(256) void emit_kernel(
    const float* __restrict__ x, const float* __restrict__ ws,
    float* __restrict__ out) {
  int gtid = blockIdx.x * 256 + threadIdx.x;
  int row  = gtid >> 6;          // b*TLEN + j
  int lane = gtid & 63;
  int b = row >> 12;             // / TLEN
  int j = row & (TLEN - 1);
  int n = ((const int*)ws)[OFF_NF + b];
  int keep = n > 0 ? n : 1;
  float4 acc = make_float4(0.f, 0.f, 0.f, 0.f);
  if (j < keep) {
    const int* fpos = (const int*)ws + OFF_FPOS + b * TLEN;
    int t_lo = j ? fpos[j - 1] : 0;
    int t_hi = (j < n) ? fpos[j] : TLEN - 1;          // n==0: whole-seq hacc_f
    const float* w1 = ws + OFF_W1 + b * TLEN;
    const float* w2 = ws + OFF_W2 + b * TLEN;
    for (int t = t_lo; t <= t_hi; ++t) {
      float w = (j && t == t_lo) ? w2[t] : w1[t];
      float4 xv = *(const float4*)(x + ((size_t)b * TLEN + t) * FEAT + lane * 4);
      acc.x = fmaf(w, xv.x, acc.x);
      acc.y = fmaf(w, xv.y, acc.y);
      acc.z = fmaf(w, xv.z, acc.z);
      acc.w = fmaf(w, xv.w, acc.w);
    }
  }
  *(float4*)(out + (size_t)row * FEAT + lane * 4) = acc;
}

extern "C" void kernel_launch(void* const* d_in, const int* in_sizes, int n_in,
                              void* d_out, int out_size, void* d_ws, size_t ws_size,
                              hipStream_t stream) {
  const float* x      = (const float*)d_in[0];
  const float* conv_w = (const float*)d_in[1];
  const float* conv_b = (const float*)d_in[2];
  const float* lin_w  = (const float*)d_in[3];
  const float* lin_b  = (const float*)d_in[4];
  float* out = (float*)d_out;
  float* ws  = (float*)d_ws;

  hipLaunchKernelGGL(weff1_kernel, dim3(40), dim3(256), 0, stream,
                     conv_w, lin_w, ws);
  hipLaunchKernelGGL(weff2_kernel, dim3(6), dim3(256), 0, stream,
                     conv_b, lin_w, lin_b, ws);
  hipLaunchKernelGGL(pdot_kernel, dim3(NROWS / 32), dim3(256), 0, stream, x, ws);
  hipLaunchKernelGGL(scan_kernel, dim3(NB), dim3(256), 0, stream, ws, out);
  hipLaunchKernelGGL(emit_kernel, dim3(NROWS / 4), dim3(256), 0, stream, x, ws, out);
}

// Round 3
// 155.099 us; speedup vs baseline: 1.0885x; 1.0663x over previous
//
#include <hip/hip_runtime.h>
#include <math.h>

#define FEAT 256
#define NB   16
#define TLEN 4096
#define NROWS (NB * TLEN)

// ws layout (element offsets, 4B elements)
#define OFF_WEFF 0                        // float[5][256]
#define OFF_BEFF 1280                     // float
#define OFF_P    2048                     // float[5][NB][TLEN]
#define OFF_W1   (OFF_P + 5 * NROWS)      // float[NB][TLEN]
#define OFF_W2   (OFF_W1 + NROWS)         // float[NB][TLEN]
#define OFF_FPOS (OFF_W2 + NROWS)         // int[NB][TLEN]
#define OFF_NF   (OFF_FPOS + NROWS)       // int[NB]
#define OFF_PART (OFF_NF + 16)            // float[8][1280] weff partials
#define OFF_ALPHA (OFF_PART + 8 * 1280)   // float[NB][TLEN]
#define OFF_CSUM (OFF_ALPHA + NROWS)      // double[NB][16] (even float offset)

// Kernel A1: partial sums over o-chunks for w_eff.
__global__ __launch_bounds__(256) void weff1_kernel(
    const float* __restrict__ conv_w, const float* __restrict__ lin_w,
    float* __restrict__ ws) {
  int ob = blockIdx.x % 5, oc = blockIdx.x / 5;
  int idx = ob * 256 + threadIdx.x;      // idx = i*5 + k (coalesced over o-rows)
  float acc = 0.f;
  int o0 = oc * 32;
#pragma unroll 8
  for (int o = o0; o < o0 + 32; ++o)
    acc = fmaf(conv_w[o * (FEAT * 5) + idx], lin_w[o], acc);
  ws[OFF_PART + oc * 1280 + idx] = acc;
}

// Kernel A2: reduce 8 partials -> w_eff[k][i]; block 5 computes b_eff.
__global__ __launch_bounds__(256) void weff2_kernel(
    const float* __restrict__ conv_b, const float* __restrict__ lin_w,
    const float* __restrict__ lin_b, float* __restrict__ ws) {
  if (blockIdx.x < 5) {
    int idx = blockIdx.x * 256 + threadIdx.x;
    float acc = 0.f;
#pragma unroll
    for (int c = 0; c < 8; ++c) acc += ws[OFF_PART + c * 1280 + idx];
    int i = idx / 5, k = idx - i * 5;
    ws[OFF_WEFF + k * FEAT + i] = acc;
  } else {
    __shared__ float red[256];
    red[threadIdx.x] = conv_b[threadIdx.x] * lin_w[threadIdx.x];
    __syncthreads();
    for (int s = 128; s > 0; s >>= 1) {
      if (threadIdx.x < s) red[threadIdx.x] += red[threadIdx.x + s];
      __syncthreads();
    }
    if (threadIdx.x == 0) ws[OFF_BEFF] = red[0] + lin_b[0];
  }
}

// Kernel B: P[k][row] = dot(x[row,:], w_eff[k,:]).  8-lane groups own one
// row each; 3 shfl levels per k.
__global__ __launch_bounds__(256) void pdot_kernel(
    const float* __restrict__ x, float* __restrict__ ws) {
  int tid  = threadIdx.x;
  int wave = tid >> 6, l = tid & 63;
  int row  = blockIdx.x * 32 + wave * 8 + (l >> 3);
  int l8   = l & 7;
  const float* xr = x + (size_t)row * FEAT + l8 * 4;
  float p[5] = {0.f, 0.f, 0.f, 0.f, 0.f};
#pragma unroll
  for (int pass = 0; pass < 8; ++pass) {
    float4 xv = *(const float4*)(xr + pass * 32);
#pragma unroll
    for (int k = 0; k < 5; ++k) {
      float4 w4 = *(const float4*)(ws + OFF_WEFF + k * FEAT + pass * 32 + l8 * 4);
      p[k] = fmaf(xv.x, w4.x, fmaf(xv.y, w4.y,
              fmaf(xv.z, w4.z, fmaf(xv.w, w4.w, p[k]))));
    }
  }
#pragma unroll
  for (int k = 0; k < 5; ++k) {
    p[k] += __shfl_xor(p[k], 1);
    p[k] += __shfl_xor(p[k], 2);
    p[k] += __shfl_xor(p[k], 4);
  }
  if (l8 == 0) {
#pragma unroll
    for (int k = 0; k < 5; ++k) ws[OFF_P + (size_t)k * NROWS + row] = p[k];
  }
}

// Kernel C1: block = (batch b, chunk of 256 steps).  Compute alpha, scan it
// (Hillis-Steele f64), store alpha and the chunk total sS[255].  Using the
// Hillis result as the chunk sum makes scanB's S-sequence EXACTLY consistent
// across chunk boundaries (fires bijective with fpos writes).
__global__ __launch_bounds__(256) void scanA_kernel(float* __restrict__ ws) {
  const int b = blockIdx.x >> 4, chunk = blockIdx.x & 15;
  const int tid = threadIdx.x;
  const int t = chunk * 256 + tid;
  float z = ws[OFF_BEFF];
#pragma unroll
  for (int k = 0; k < 5; ++k) {
    int tt = t + k - 2;
    if (tt >= 0 && tt < TLEN) z += ws[OFF_P + (size_t)k * NROWS + b * TLEN + tt];
  }
  float a = 1.f / (1.f + expf(-z));
  ws[OFF_ALPHA + b * TLEN + t] = a;

  __shared__ double sS[256];
  sS[tid] = (double)a;
  __syncthreads();
  for (int s = 1; s < 256; s <<= 1) {
    double add = (tid >= s) ? sS[tid - s] : 0.0;
    __syncthreads();
    sS[tid] += add;
    __syncthreads();
  }
  if (tid == 255)
    ((double*)ws)[OFF_CSUM / 2 + b * 16 + chunk] = sS[255];
}

// Kernel C2: block = (b, chunk).  offset = serial left-fold of csum[0..chunk)
// (identical fold order in every block -> exact chunk-boundary consistency);
// Hillis-Steele scan of this chunk's 256 alphas; one thread per timestep
// emits w1/w2/fpos; last thread of last chunk emits n and the len output.
__global__ __launch_bounds__(256) void scanB_kernel(
    float* __restrict__ ws, float* __restrict__ out) {
  const int b = blockIdx.x >> 4, chunk = blockIdx.x & 15;
  const int tid = threadIdx.x;
  const int t = chunk * 256 + tid;
  const double* csum = (const double*)ws + OFF_CSUM / 2 + b * 16;
  double offset = 0.0;
  for (int c = 0; c < chunk; ++c) offset += csum[c];

  double a = (double)ws[OFF_ALPHA + b * TLEN + t];
  __shared__ double sS[256];
  sS[tid] = a;
  __syncthreads();
  for (int s = 1; s < 256; s <<= 1) {
    double add = (tid >= s) ? sS[tid - s] : 0.0;
    __syncthreads();
    sS[tid] += add;
    __syncthreads();
  }
  double St = offset + sS[tid];
  double Sp = tid ? offset + sS[tid - 1] : offset;   // == St of t-1, exactly
  double Ft = floor(St), Fp = floor(Sp);

  ws[OFF_W1 + b * TLEN + t] = (float)(fmin(St, Fp + 1.0) - Sp);  // alpha or a1
  if (Ft > Fp) {
    ws[OFF_W2 + b * TLEN + t] = (float)(St - Ft);                // a2
    ((int*)ws)[OFF_FPOS + b * TLEN + (int)Ft - 1] = t;           // fire pos
  }
  if (chunk == 15 && tid == 255) {
    int n = (int)Ft;
    ((int*)ws)[OFF_NF + b] = n;
    out[(size_t)NROWS * FEAT + b] = (float)(n > 0 ? n : 1);      // len output
  }
}

// Kernel D: one wave per output row j: gather weighted segment
// [t_lo..t_hi] of x; rows >= keep are zeros (d_out is poisoned).
__global__ __launch_bounds__(256) void emit_kernel(
    const float* __restrict__ x, const float* __restrict__ ws,
    float* __restrict__ out) {
  int gtid = blockIdx.x * 256 + threadIdx.x;
  int row  = gtid >> 6;          // b*TLEN + j
  int lane = gtid & 63;
  int b = row >> 12;             // / TLEN
  int j = row & (TLEN - 1);
  int n = ((const int*)ws)[OFF_NF + b];
  int keep = n > 0 ? n : 1;
  float4 acc = make_float4(0.f, 0.f, 0.f, 0.f);
  if (j < keep) {
    const int* fpos = (const int*)ws + OFF_FPOS + b * TLEN;
    int t_lo = j ? fpos[j - 1] : 0;
    int t_hi = (j < n) ? fpos[j] : TLEN - 1;          // n==0: whole-seq hacc_f
    const float* w1 = ws + OFF_W1 + b * TLEN;
    const float* w2 = ws + OFF_W2 + b * TLEN;
    for (int t = t_lo; t <= t_hi; ++t) {
      float w = (j && t == t_lo) ? w2[t] : w1[t];
      float4 xv = *(const float4*)(x + ((size_t)b * TLEN + t) * FEAT + lane * 4);
      acc.x = fmaf(w, xv.x, acc.x);
      acc.y = fmaf(w, xv.y, acc.y);
      acc.z = fmaf(w, xv.z, acc.z);
      acc.w = fmaf(w, xv.w, acc.w);
    }
  }
  *(float4*)(out + (size_t)row * FEAT + lane * 4) = acc;
}

extern "C" void kernel_launch(void* const* d_in, const int* in_sizes, int n_in,
                              void* d_out, int out_size, void* d_ws, size_t ws_size,
                              hipStream_t stream) {
  const float* x      = (const float*)d_in[0];
  const float* conv_w = (const float*)d_in[1];
  const float* conv_b = (const float*)d_in[2];
  const float* lin_w  = (const float*)d_in[3];
  const float* lin_b  = (const float*)d_in[4];
  float* out = (float*)d_out;
  float* ws  = (float*)d_ws;

  hipLaunchKernelGGL(weff1_kernel, dim3(40), dim3(256), 0, stream,
                     conv_w, lin_w, ws);
  hipLaunchKernelGGL(weff2_kernel, dim3(6), dim3(256), 0, stream,
                     conv_b, lin_w, lin_b, ws);
  hipLaunchKernelGGL(pdot_kernel, dim3(NROWS / 32), dim3(256), 0, stream, x, ws);
  hipLaunchKernelGGL(scanA_kernel, dim3(NB * 16), dim3(256), 0, stream, ws);
  hipLaunchKernelGGL(scanB_kernel, dim3(NB * 16), dim3(256), 0, stream, ws, out);
  hipLaunchKernelGGL(emit_kernel, dim3(NROWS / 4), dim3(256), 0, stream, x, ws, out);
}